// Round 3
// baseline (443.059 us; speedup 1.0000x reference)
//
#include <hip/hip_runtime.h>
#include <hip/hip_bf16.h>
#include <math.h>

#define D_MODEL    1024
#define EXPERT_DIM 4096
#define N_EXPERTS  8
#define N_TOKENS   4096
#define M_TILE     128
#define MAX_TILES  40

typedef __attribute__((ext_vector_type(8))) short short8;
typedef __attribute__((ext_vector_type(4))) float f32x4;

// workspace byte offsets
#define OFF_PROBS   0u
#define OFF_EXP     131072u
#define OFF_GATE    147456u
#define OFF_CNT     163840u
#define OFF_CUR     163872u
#define OFF_OFFS    163904u
#define OFF_NT      163940u
#define OFF_TE      164096u
#define OFF_TR      164352u
#define OFF_BUCKET  164608u
#define OFF_XB      262144u      // 4096*1024 bf16 = 8 MiB
#define OFF_H       8650752u     // 4096*4096 bf16 = 32 MiB
#define OFF_W1B     42205184u    // 8*4096*1024 bf16 = 64 MiB
#define OFF_W3B     109314048u
#define OFF_W2B     176422912u
#define END_W3B     176422912ull
#define END_W2B     243531776ull

#define GLOAD_LDS16(gp, lp) \
  __builtin_amdgcn_global_load_lds((const __attribute__((address_space(1))) void*)(gp), \
                                   (__attribute__((address_space(3))) void*)(lp), 16, 0, 0)

static __device__ __forceinline__ ushort f2b(float f) {
  union { __hip_bfloat16 h; ushort u; } c;
  c.h = __float2bfloat16(f);
  return c.u;
}

static __device__ __forceinline__ short8 pack8(float4 a, float4 b) {
  short8 r;
  r[0] = (short)f2b(a.x); r[1] = (short)f2b(a.y);
  r[2] = (short)f2b(a.z); r[3] = (short)f2b(a.w);
  r[4] = (short)f2b(b.x); r[5] = (short)f2b(b.y);
  r[6] = (short)f2b(b.z); r[7] = (short)f2b(b.w);
  return r;
}

// ---------------- fp32 -> bf16 weight cast ----------------
__global__ __launch_bounds__(256) void cast_kernel(
    const float* __restrict__ src, ushort* __restrict__ dst, int n8) {
  int i = blockIdx.x * blockDim.x + threadIdx.x;
  int stride = gridDim.x * blockDim.x;
  for (; i < n8; i += stride) {
    const float4* s = (const float4*)(src + (size_t)i * 8);
    float4 a = s[0], b = s[1];
    *(short8*)(dst + (size_t)i * 8) = pack8(a, b);
  }
}

// ---------------- gating (fp32, exact argmax) + x -> bf16 cast ----------------
__global__ __launch_bounds__(256) void gate_kernel(
    const float* __restrict__ x, const float* __restrict__ gw,
    float* __restrict__ probs, int* __restrict__ tok_e,
    float* __restrict__ tok_g, int* __restrict__ cnt,
    ushort* __restrict__ xb) {
  int token = (blockIdx.x * blockDim.x + threadIdx.x) >> 6;
  int lane = threadIdx.x & 63;
  if (token >= N_TOKENS) return;
  const float* xr = x + (size_t)token * D_MODEL;
  float xv[16];
#pragma unroll
  for (int i = 0; i < 16; ++i) xv[i] = xr[lane + 64 * i];
  ushort* xo = xb + (size_t)token * D_MODEL;
#pragma unroll
  for (int i = 0; i < 16; ++i) xo[lane + 64 * i] = f2b(xv[i]);
  float logit[N_EXPERTS];
#pragma unroll
  for (int e = 0; e < N_EXPERTS; ++e) {
    const float* g = gw + e * D_MODEL;
    float s = 0.f;
#pragma unroll
    for (int i = 0; i < 16; ++i) s = fmaf(xv[i], g[lane + 64 * i], s);
#pragma unroll
    for (int m = 32; m; m >>= 1) s += __shfl_xor(s, m, 64);
    logit[e] = s;
  }
  if (lane == 0) {
    float mx = logit[0]; int arg = 0;
#pragma unroll
    for (int e = 1; e < N_EXPERTS; ++e)
      if (logit[e] > mx) { mx = logit[e]; arg = e; }
    float pe[N_EXPERTS]; float den = 0.f;
#pragma unroll
    for (int e = 0; e < N_EXPERTS; ++e) { pe[e] = __expf(logit[e] - mx); den += pe[e]; }
    float inv = 1.f / den;
#pragma unroll
    for (int e = 0; e < N_EXPERTS; ++e) probs[token * N_EXPERTS + e] = pe[e] * inv;
    tok_e[token] = arg;
    tok_g[token] = pe[arg] * inv;
    atomicAdd(&cnt[arg], 1);
  }
}

__global__ __launch_bounds__(256) void plan_kernel(
    const float* __restrict__ probs, const int* __restrict__ cnt,
    int* __restrict__ offs, int* __restrict__ ntiles,
    int* __restrict__ tile_e, int* __restrict__ tile_r0,
    float* __restrict__ aux_out) {
  __shared__ float red[256];
  __shared__ float simp[N_EXPERTS];
  int t = threadIdx.x;
  for (int e = 0; e < N_EXPERTS; ++e) {
    float s = 0.f;
    for (int n = t; n < N_TOKENS; n += 256) s += probs[n * N_EXPERTS + e];
    red[t] = s; __syncthreads();
    for (int w = 128; w; w >>= 1) {
      if (t < w) red[t] += red[t + w];
      __syncthreads();
    }
    if (t == 0) simp[e] = red[0];
    __syncthreads();
  }
  if (t == 0) {
    int o = 0, nt = 0; float aux = 0.f;
    for (int e = 0; e < N_EXPERTS; ++e) {
      offs[e] = o;
      int c = cnt[e];
      int m = (c + M_TILE - 1) / M_TILE;
      for (int i = 0; i < m; ++i) { tile_e[nt] = e; tile_r0[nt] = i * M_TILE; ++nt; }
      aux += (float)c * simp[e];
      o += c;
    }
    offs[N_EXPERTS] = o;
    *ntiles = nt;
    *aux_out = aux * (1.f / ((float)N_TOKENS * (float)N_TOKENS)) * N_EXPERTS * 0.01f;
  }
}

__global__ __launch_bounds__(256) void scatter_kernel(
    const int* __restrict__ tok_e, int* __restrict__ cursor,
    const int* __restrict__ offs, int* __restrict__ bucket) {
  int n = blockIdx.x * blockDim.x + threadIdx.x;
  if (n >= N_TOKENS) return;
  int e = tok_e[n];
  int p = atomicAdd(&cursor[e], 1);
  bucket[offs[e] + p] = n;
}

// ======== fast path: all-bf16, all staging via global_load_lds ========
__global__ __launch_bounds__(256) void gemm1_bf16w(
    const ushort* __restrict__ xb, const ushort* __restrict__ w1b,
    const ushort* __restrict__ w3b, const int* __restrict__ ntiles,
    const int* __restrict__ tile_e, const int* __restrict__ tile_r0,
    const int* __restrict__ offs, const int* __restrict__ bucket,
    ushort* __restrict__ H) {
  int tile = blockIdx.y;
  if (tile >= *ntiles) return;
  int e = tile_e[tile], r0 = tile_r0[tile];
  int base = offs[e], cnt = offs[e + 1] - base;
  int f0 = blockIdx.x * 64;

  __shared__ ushort As[128 * 64];
  __shared__ ushort B1s[64 * 64];
  __shared__ ushort B3s[64 * 64];

  int tid = threadIdx.x;
  int w = tid >> 6, lane = tid & 63;
  int wm = w >> 1, wn = w & 1;

  const ushort* aptr[4];
#pragma unroll
  for (int c = 0; c < 4; ++c) {
    int r = w * 32 + c * 8 + (lane >> 3);
    int rr = min(r0 + r, cnt - 1);
    int tok = bucket[base + rr];
    aptr[c] = xb + (size_t)tok * D_MODEL + (lane & 7) * 8;
  }
  const ushort* b1p[2];
  const ushort* b3p[2];
#pragma unroll
  for (int c = 0; c < 2; ++c) {
    int row = f0 + w * 16 + c * 8 + (lane >> 3);
    b1p[c] = w1b + ((size_t)e * EXPERT_DIM + row) * D_MODEL + (lane & 7) * 8;
    b3p[c] = w3b + ((size_t)e * EXPERT_DIM + row) * D_MODEL + (lane & 7) * 8;
  }

  f32x4 accU[4][2], accV[4][2];
#pragma unroll
  for (int i = 0; i < 4; ++i)
#pragma unroll
    for (int j = 0; j < 2; ++j) { accU[i][j] = (f32x4)0.f; accV[i][j] = (f32x4)0.f; }

  for (int k0 = 0; k0 < D_MODEL; k0 += 64) {
#pragma unroll
    for (int c = 0; c < 4; ++c)
      GLOAD_LDS16(aptr[c] + k0, &As[(w * 32 + c * 8) * 64]);
#pragma unroll
    for (int c = 0; c < 2; ++c) {
      GLOAD_LDS16(b1p[c] + k0, &B1s[(w * 16 + c * 8) * 64]);
      GLOAD_LDS16(b3p[c] + k0, &B3s[(w * 16 + c * 8) * 64]);
    }
    __syncthreads();
#pragma unroll
    for (int ks = 0; ks < 2; ++ks) {
      int ko = ks * 32 + (lane >> 4) * 8;
      short8 af[4], bf1[2], bf3[2];
#pragma unroll
      for (int i = 0; i < 4; ++i)
        af[i] = *(const short8*)&As[(wm * 64 + i * 16 + (lane & 15)) * 64 + ko];
#pragma unroll
      for (int j = 0; j < 2; ++j) {
        bf1[j] = *(const short8*)&B1s[(wn * 32 + j * 16 + (lane & 15)) * 64 + ko];
        bf3[j] = *(const short8*)&B3s[(wn * 32 + j * 16 + (lane & 15)) * 64 + ko];
      }
#pragma unroll
      for (int i = 0; i < 4; ++i)
#pragma unroll
        for (int j = 0; j < 2; ++j) {
          accU[i][j] = __builtin_amdgcn_mfma_f32_16x16x32_bf16(af[i], bf1[j], accU[i][j], 0, 0, 0);
          accV[i][j] = __builtin_amdgcn_mfma_f32_16x16x32_bf16(af[i], bf3[j], accV[i][j], 0, 0, 0);
        }
    }
    __syncthreads();
  }
#pragma unroll
  for (int i = 0; i < 4; ++i)
#pragma unroll
    for (int q = 0; q < 4; ++q) {
      int m_loc = wm * 64 + i * 16 + (lane >> 4) * 4 + q;
      if (r0 + m_loc < cnt) {
        size_t rowb = (size_t)(base + r0 + m_loc) * EXPERT_DIM + f0 + wn * 32 + (lane & 15);
#pragma unroll
        for (int j = 0; j < 2; ++j) {
          float uu = accU[i][j][q], vv = accV[i][j][q];
          float h = uu / (1.f + __expf(-uu)) * vv;
          H[rowb + j * 16] = f2b(h);
        }
      }
    }
}

__global__ __launch_bounds__(256) void gemm2_bf16w(
    const ushort* __restrict__ H, const ushort* __restrict__ w2b,
    const int* __restrict__ ntiles, const int* __restrict__ tile_e,
    const int* __restrict__ tile_r0, const int* __restrict__ offs,
    const int* __restrict__ bucket, const float* __restrict__ tok_g,
    float* __restrict__ out) {
  int tile = blockIdx.y;
  if (tile >= *ntiles) return;
  int e = tile_e[tile], r0 = tile_r0[tile];
  int base = offs[e], cnt = offs[e + 1] - base;
  int d0 = blockIdx.x * 64;

  __shared__ ushort As[128 * 64];
  __shared__ ushort Bs[64 * 64];

  int tid = threadIdx.x;
  int w = tid >> 6, lane = tid & 63;
  int wm = w >> 1, wn = w & 1;

  const ushort* aptr[4];
#pragma unroll
  for (int c = 0; c < 4; ++c) {
    int r = w * 32 + c * 8 + (lane >> 3);
    int rr = min(r0 + r, cnt - 1);
    aptr[c] = H + (size_t)(base + rr) * EXPERT_DIM + (lane & 7) * 8;
  }
  const ushort* b2p[2];
#pragma unroll
  for (int c = 0; c < 2; ++c) {
    int row = d0 + w * 16 + c * 8 + (lane >> 3);
    b2p[c] = w2b + ((size_t)e * D_MODEL + row) * EXPERT_DIM + (lane & 7) * 8;
  }

  f32x4 acc[4][2];
#pragma unroll
  for (int i = 0; i < 4; ++i)
#pragma unroll
    for (int j = 0; j < 2; ++j) acc[i][j] = (f32x4)0.f;

  for (int k0 = 0; k0 < EXPERT_DIM; k0 += 64) {
#pragma unroll
    for (int c = 0; c < 4; ++c)
      GLOAD_LDS16(aptr[c] + k0, &As[(w * 32 + c * 8) * 64]);
#pragma unroll
    for (int c = 0; c < 2; ++c)
      GLOAD_LDS16(b2p[c] + k0, &Bs[(w * 16 + c * 8) * 64]);
    __syncthreads();
#pragma unroll
    for (int ks = 0; ks < 2; ++ks) {
      int ko = ks * 32 + (lane >> 4) * 8;
      short8 af[4], bf[2];
#pragma unroll
      for (int i = 0; i < 4; ++i)
        af[i] = *(const short8*)&As[(wm * 64 + i * 16 + (lane & 15)) * 64 + ko];
#pragma unroll
      for (int j = 0; j < 2; ++j)
        bf[j] = *(const short8*)&Bs[(wn * 32 + j * 16 + (lane & 15)) * 64 + ko];
#pragma unroll
      for (int i = 0; i < 4; ++i)
#pragma unroll
        for (int j = 0; j < 2; ++j)
          acc[i][j] = __builtin_amdgcn_mfma_f32_16x16x32_bf16(af[i], bf[j], acc[i][j], 0, 0, 0);
    }
    __syncthreads();
  }
#pragma unroll
  for (int i = 0; i < 4; ++i)
#pragma unroll
    for (int q = 0; q < 4; ++q) {
      int m_loc = wm * 64 + i * 16 + (lane >> 4) * 4 + q;
      if (r0 + m_loc < cnt) {
        int tok = bucket[base + r0 + m_loc];
        float g = tok_g[tok];
        float* op = out + (size_t)tok * D_MODEL + d0 + wn * 32 + (lane & 15);
#pragma unroll
        for (int j = 0; j < 2; ++j)
          op[j * 16] = acc[i][j][q] * g;
      }
    }
}

// ======== fallback path: on-the-fly fp32->bf16 B staging (round-2 kernels) ========
__global__ __launch_bounds__(256) void gemm1_f32w(
    const ushort* __restrict__ xb, const float* __restrict__ w1,
    const float* __restrict__ w3, const int* __restrict__ ntiles,
    const int* __restrict__ tile_e, const int* __restrict__ tile_r0,
    const int* __restrict__ offs, const int* __restrict__ bucket,
    ushort* __restrict__ H) {
  int tile = blockIdx.y;
  if (tile >= *ntiles) return;
  int e = tile_e[tile], r0 = tile_r0[tile];
  int base = offs[e], cnt = offs[e + 1] - base;
  int f0 = blockIdx.x * 64;

  __shared__ ushort As[128 * 64];
  __shared__ ushort B1s[64 * 64];
  __shared__ ushort B3s[64 * 64];

  int tid = threadIdx.x;
  int w = tid >> 6, lane = tid & 63;
  int wm = w >> 1, wn = w & 1;

  const ushort* aptr[4];
#pragma unroll
  for (int c = 0; c < 4; ++c) {
    int r = w * 32 + c * 8 + (lane >> 3);
    int rr = min(r0 + r, cnt - 1);
    int tok = bucket[base + rr];
    aptr[c] = xb + (size_t)tok * D_MODEL + (lane & 7) * 8;
  }
  int rb = tid >> 2, qb = tid & 3;
  const float4* p1 = (const float4*)(w1 + ((size_t)e * EXPERT_DIM + f0 + rb) * D_MODEL + qb * 16);
  const float4* p3 = (const float4*)(w3 + ((size_t)e * EXPERT_DIM + f0 + rb) * D_MODEL + qb * 16);
  ushort* wb1 = &B1s[rb * 64 + qb * 16];
  ushort* wb3 = &B3s[rb * 64 + qb * 16];

  f32x4 accU[4][2], accV[4][2];
#pragma unroll
  for (int i = 0; i < 4; ++i)
#pragma unroll
    for (int j = 0; j < 2; ++j) { accU[i][j] = (f32x4)0.f; accV[i][j] = (f32x4)0.f; }

  for (int k0 = 0; k0 < D_MODEL; k0 += 64) {
#pragma unroll
    for (int c = 0; c < 4; ++c)
      GLOAD_LDS16(aptr[c] + k0, &As[(w * 32 + c * 8) * 64]);
    const float4* q1 = p1 + (k0 >> 2);
    const float4* q3 = p3 + (k0 >> 2);
    float4 u0 = q1[0], u1 = q1[1], u2 = q1[2], u3 = q1[3];
    float4 v0 = q3[0], v1 = q3[1], v2 = q3[2], v3 = q3[3];
    *(short8*)wb1       = pack8(u0, u1);
    *(short8*)(wb1 + 8) = pack8(u2, u3);
    *(short8*)wb3       = pack8(v0, v1);
    *(short8*)(wb3 + 8) = pack8(v2, v3);
    __syncthreads();
#pragma unroll
    for (int ks = 0; ks < 2; ++ks) {
      int ko = ks * 32 + (lane >> 4) * 8;
      short8 af[4], bf1[2], bf3[2];
#pragma unroll
      for (int i = 0; i < 4; ++i)
        af[i] = *(const short8*)&As[(wm * 64 + i * 16 + (lane & 15)) * 64 + ko];
#pragma unroll
      for (int j = 0; j < 2; ++j) {
        bf1[j] = *(const short8*)&B1s[(wn * 32 + j * 16 + (lane & 15)) * 64 + ko];
        bf3[j] = *(const short8*)&B3s[(wn * 32 + j * 16 + (lane & 15)) * 64 + ko];
      }
#pragma unroll
      for (int i = 0; i < 4; ++i)
#pragma unroll
        for (int j = 0; j < 2; ++j) {
          accU[i][j] = __builtin_amdgcn_mfma_f32_16x16x32_bf16(af[i], bf1[j], accU[i][j], 0, 0, 0);
          accV[i][j] = __builtin_amdgcn_mfma_f32_16x16x32_bf16(af[i], bf3[j], accV[i][j], 0, 0, 0);
        }
    }
    __syncthreads();
  }
#pragma unroll
  for (int i = 0; i < 4; ++i)
#pragma unroll
    for (int q = 0; q < 4; ++q) {
      int m_loc = wm * 64 + i * 16 + (lane >> 4) * 4 + q;
      if (r0 + m_loc < cnt) {
        size_t rowb = (size_t)(base + r0 + m_loc) * EXPERT_DIM + f0 + wn * 32 + (lane & 15);
#pragma unroll
        for (int j = 0; j < 2; ++j) {
          float uu = accU[i][j][q], vv = accV[i][j][q];
          float h = uu / (1.f + __expf(-uu)) * vv;
          H[rowb + j * 16] = f2b(h);
        }
      }
    }
}

__global__ __launch_bounds__(256) void gemm2_f32w(
    const ushort* __restrict__ H, const float* __restrict__ w2,
    const int* __restrict__ ntiles, const int* __restrict__ tile_e,
    const int* __restrict__ tile_r0, const int* __restrict__ offs,
    const int* __restrict__ bucket, const float* __restrict__ tok_g,
    float* __restrict__ out) {
  int tile = blockIdx.y;
  if (tile >= *ntiles) return;
  int e = tile_e[tile], r0 = tile_r0[tile];
  int base = offs[e], cnt = offs[e + 1] - base;
  int d0 = blockIdx.x * 64;

  __shared__ ushort As[128 * 64];
  __shared__ ushort Bs[64 * 64];

  int tid = threadIdx.x;
  int w = tid >> 6, lane = tid & 63;
  int wm = w >> 1, wn = w & 1;

  const ushort* aptr[4];
#pragma unroll
  for (int c = 0; c < 4; ++c) {
    int r = w * 32 + c * 8 + (lane >> 3);
    int rr = min(r0 + r, cnt - 1);
    aptr[c] = H + (size_t)(base + rr) * EXPERT_DIM + (lane & 7) * 8;
  }
  int rb = tid >> 2, qb = tid & 3;
  const float4* p2 = (const float4*)(w2 + ((size_t)e * D_MODEL + d0 + rb) * EXPERT_DIM + qb * 16);
  ushort* wb = &Bs[rb * 64 + qb * 16];

  f32x4 acc[4][2];
#pragma unroll
  for (int i = 0; i < 4; ++i)
#pragma unroll
    for (int j = 0; j < 2; ++j) acc[i][j] = (f32x4)0.f;

  for (int k0 = 0; k0 < EXPERT_DIM; k0 += 64) {
#pragma unroll
    for (int c = 0; c < 4; ++c)
      GLOAD_LDS16(aptr[c] + k0, &As[(w * 32 + c * 8) * 64]);
    const float4* q = p2 + (k0 >> 2);
    float4 u0 = q[0], u1 = q[1], u2 = q[2], u3 = q[3];
    *(short8*)wb       = pack8(u0, u1);
    *(short8*)(wb + 8) = pack8(u2, u3);
    __syncthreads();
#pragma unroll
    for (int ks = 0; ks < 2; ++ks) {
      int ko = ks * 32 + (lane >> 4) * 8;
      short8 af[4], bf[2];
#pragma unroll
      for (int i = 0; i < 4; ++i)
        af[i] = *(const short8*)&As[(wm * 64 + i * 16 + (lane & 15)) * 64 + ko];
#pragma unroll
      for (int j = 0; j < 2; ++j)
        bf[j] = *(const short8*)&Bs[(wn * 32 + j * 16 + (lane & 15)) * 64 + ko];
#pragma unroll
      for (int i = 0; i < 4; ++i)
#pragma unroll
        for (int j = 0; j < 2; ++j)
          acc[i][j] = __builtin_amdgcn_mfma_f32_16x16x32_bf16(af[i], bf[j], acc[i][j], 0, 0, 0);
    }
    __syncthreads();
  }
#pragma unroll
  for (int i = 0; i < 4; ++i)
#pragma unroll
    for (int q = 0; q < 4; ++q) {
      int m_loc = wm * 64 + i * 16 + (lane >> 4) * 4 + q;
      if (r0 + m_loc < cnt) {
        int tok = bucket[base + r0 + m_loc];
        float g = tok_g[tok];
        float* op = out + (size_t)tok * D_MODEL + d0 + wn * 32 + (lane & 15);
#pragma unroll
        for (int j = 0; j < 2; ++j)
          op[j * 16] = acc[i][j][q] * g;
      }
    }
}

extern "C" void kernel_launch(void* const* d_in, const int* in_sizes, int n_in,
                              void* d_out, int out_size, void* d_ws, size_t ws_size,
                              hipStream_t stream) {
  const float* x  = (const float*)d_in[0];
  const float* gw = (const float*)d_in[1];
  const float* w1 = (const float*)d_in[2];
  const float* w2 = (const float*)d_in[3];
  const float* w3 = (const float*)d_in[4];
  float* out = (float*)d_out;
  char* ws = (char*)d_ws;

  float* probs = (float*)(ws + OFF_PROBS);
  int* tok_e   = (int*)(ws + OFF_EXP);
  float* tok_g = (float*)(ws + OFF_GATE);
  int* cnt     = (int*)(ws + OFF_CNT);
  int* cur     = (int*)(ws + OFF_CUR);
  int* offs    = (int*)(ws + OFF_OFFS);
  int* ntiles  = (int*)(ws + OFF_NT);
  int* tile_e  = (int*)(ws + OFF_TE);
  int* tile_r0 = (int*)(ws + OFF_TR);
  int* bucket  = (int*)(ws + OFF_BUCKET);
  ushort* xb   = (ushort*)(ws + OFF_XB);
  ushort* H    = (ushort*)(ws + OFF_H);
  ushort* w1b  = (ushort*)(ws + OFF_W1B);
  ushort* w3b  = (ushort*)(ws + OFF_W3B);
  ushort* w2b  = (ushort*)(ws + OFF_W2B);

  const bool pre13 = ws_size >= END_W3B;   // w1b+w3b fit
  const bool pre2  = ws_size >= END_W2B;   // w2b also fits
  const int n8w1 = N_EXPERTS * EXPERT_DIM * D_MODEL / 8;

  hipMemsetAsync(ws + OFF_CNT, 0, 64, stream);  // cnt + cursor
  if (pre13) {
    cast_kernel<<<2048, 256, 0, stream>>>(w1, w1b, n8w1);
    cast_kernel<<<2048, 256, 0, stream>>>(w3, w3b, n8w1);
  }
  if (pre2)
    cast_kernel<<<2048, 256, 0, stream>>>(w2, w2b, n8w1);

  gate_kernel<<<N_TOKENS / 4, 256, 0, stream>>>(x, gw, probs, tok_e, tok_g, cnt, xb);
  plan_kernel<<<1, 256, 0, stream>>>(probs, cnt, offs, ntiles, tile_e, tile_r0,
                                     out + (size_t)N_TOKENS * D_MODEL);
  scatter_kernel<<<N_TOKENS / 256, 256, 0, stream>>>(tok_e, cur, offs, bucket);

  if (pre13)
    gemm1_bf16w<<<dim3(EXPERT_DIM / 64, MAX_TILES), 256, 0, stream>>>(
        xb, w1b, w3b, ntiles, tile_e, tile_r0, offs, bucket, H);
  else
    gemm1_f32w<<<dim3(EXPERT_DIM / 64, MAX_TILES), 256, 0, stream>>>(
        xb, w1, w3, ntiles, tile_e, tile_r0, offs, bucket, H);

  if (pre2)
    gemm2_bf16w<<<dim3(D_MODEL / 64, MAX_TILES), 256, 0, stream>>>(
        H, w2b, ntiles, tile_e, tile_r0, offs, bucket, tok_g, out);
  else
    gemm2_f32w<<<dim3(D_MODEL / 64, MAX_TILES), 256, 0, stream>>>(
        H, w2, ntiles, tile_e, tile_r0, offs, bucket, tok_g, out);
}

// Round 4
// 377.972 us; speedup vs baseline: 1.1722x; 1.1722x over previous
//
#include <hip/hip_runtime.h>
#include <hip/hip_bf16.h>
#include <math.h>

#define D_MODEL    1024
#define EXPERT_DIM 4096
#define N_EXPERTS  8
#define N_TOKENS   4096
#define M_TILE     128
#define MAX_TILES  40

typedef __attribute__((ext_vector_type(8))) short short8;
typedef __attribute__((ext_vector_type(4))) float f32x4;

// workspace byte offsets
#define OFF_PROBS   0u
#define OFF_EXP     131072u
#define OFF_GATE    147456u
#define OFF_CNT     163840u     // 8 i32
#define OFF_CUR     163872u     // 8 i32
#define OFF_SIMP    163904u     // 8 f32
#define OFF_OFFS    163936u     // 9 i32
#define OFF_NT      163976u     // 1 i32
#define OFF_TE      164096u     // 40 i32
#define OFF_TR      164352u     // 40 i32
#define OFF_BUCKET  164608u     // 4096 i32
#define OFF_XB      262144u     // 4096*1024 bf16 = 8 MiB
#define OFF_H       8650752u    // 4096*4096 bf16 = 32 MiB (ends ~40.3 MiB)

#define GLOAD_LDS16(gp, lp) \
  __builtin_amdgcn_global_load_lds((const __attribute__((address_space(1))) void*)(gp), \
                                   (__attribute__((address_space(3))) void*)(lp), 16, 0, 0)

static __device__ __forceinline__ ushort f2b(float f) {
  union { __hip_bfloat16 h; ushort u; } c;
  c.h = __float2bfloat16(f);
  return c.u;
}

static __device__ __forceinline__ short8 pack8(float4 a, float4 b) {
  short8 r;
  r[0] = (short)f2b(a.x); r[1] = (short)f2b(a.y);
  r[2] = (short)f2b(a.z); r[3] = (short)f2b(a.w);
  r[4] = (short)f2b(b.x); r[5] = (short)f2b(b.y);
  r[6] = (short)f2b(b.z); r[7] = (short)f2b(b.w);
  return r;
}

// ---------------- gating (fp32, exact argmax) + x -> bf16 cast ----------------
__global__ __launch_bounds__(256) void gate_kernel(
    const float* __restrict__ x, const float* __restrict__ gw,
    float* __restrict__ probs, int* __restrict__ tok_e,
    float* __restrict__ tok_g, int* __restrict__ cnt,
    ushort* __restrict__ xb) {
  int token = (blockIdx.x * blockDim.x + threadIdx.x) >> 6;
  int lane = threadIdx.x & 63;
  if (token >= N_TOKENS) return;
  const float* xr = x + (size_t)token * D_MODEL;
  float xv[16];
#pragma unroll
  for (int i = 0; i < 16; ++i) xv[i] = xr[lane + 64 * i];
  ushort* xo = xb + (size_t)token * D_MODEL;
#pragma unroll
  for (int i = 0; i < 16; ++i) xo[lane + 64 * i] = f2b(xv[i]);
  float logit[N_EXPERTS];
#pragma unroll
  for (int e = 0; e < N_EXPERTS; ++e) {
    const float* g = gw + e * D_MODEL;
    float s = 0.f;
#pragma unroll
    for (int i = 0; i < 16; ++i) s = fmaf(xv[i], g[lane + 64 * i], s);
#pragma unroll
    for (int m = 32; m; m >>= 1) s += __shfl_xor(s, m, 64);
    logit[e] = s;
  }
  if (lane == 0) {
    float mx = logit[0]; int arg = 0;
#pragma unroll
    for (int e = 1; e < N_EXPERTS; ++e)
      if (logit[e] > mx) { mx = logit[e]; arg = e; }
    float pe[N_EXPERTS]; float den = 0.f;
#pragma unroll
    for (int e = 0; e < N_EXPERTS; ++e) { pe[e] = __expf(logit[e] - mx); den += pe[e]; }
    float inv = 1.f / den;
#pragma unroll
    for (int e = 0; e < N_EXPERTS; ++e) probs[token * N_EXPERTS + e] = pe[e] * inv;
    tok_e[token] = arg;
    tok_g[token] = pe[arg] * inv;
    atomicAdd(&cnt[arg], 1);
  }
}

// ---------------- importance reduction (parallel) ----------------
__global__ __launch_bounds__(256) void imp_kernel(
    const float* __restrict__ probs, float* __restrict__ simp) {
  int row = blockIdx.x * 256 + threadIdx.x;
  const float4* p = (const float4*)(probs + (size_t)row * N_EXPERTS);
  float4 a = p[0], b = p[1];
  float v[8] = {a.x, a.y, a.z, a.w, b.x, b.y, b.z, b.w};
#pragma unroll
  for (int m = 32; m; m >>= 1)
#pragma unroll
    for (int i = 0; i < 8; ++i) v[i] += __shfl_xor(v[i], m, 64);
  if ((threadIdx.x & 63) == 0)
#pragma unroll
    for (int i = 0; i < 8; ++i) atomicAdd(&simp[i], v[i]);
}

__global__ void plan_kernel(
    const int* __restrict__ cnt, const float* __restrict__ simp,
    int* __restrict__ offs, int* __restrict__ ntiles,
    int* __restrict__ tile_e, int* __restrict__ tile_r0,
    float* __restrict__ aux_out) {
  if (threadIdx.x == 0 && blockIdx.x == 0) {
    int o = 0, nt = 0; float aux = 0.f;
    for (int e = 0; e < N_EXPERTS; ++e) {
      offs[e] = o;
      int c = cnt[e];
      int m = (c + M_TILE - 1) / M_TILE;
      for (int i = 0; i < m; ++i) { tile_e[nt] = e; tile_r0[nt] = i * M_TILE; ++nt; }
      aux += (float)c * simp[e];
      o += c;
    }
    offs[N_EXPERTS] = o;
    *ntiles = nt;
    *aux_out = aux * (1.f / ((float)N_TOKENS * (float)N_TOKENS)) * N_EXPERTS * 0.01f;
  }
}

__global__ __launch_bounds__(256) void scatter_kernel(
    const int* __restrict__ tok_e, int* __restrict__ cursor,
    const int* __restrict__ offs, int* __restrict__ bucket) {
  int n = blockIdx.x * blockDim.x + threadIdx.x;
  if (n >= N_TOKENS) return;
  int e = tok_e[n];
  int p = atomicAdd(&cursor[e], 1);
  bucket[offs[e] + p] = n;
}

// ---- GEMM1: H = silu(x@w1^T) * (x@w3^T); 128x64 tile; dbuf pipeline ----
// A (bf16) via global_load_lds (dbuf); B (fp32 w1/w3) reg-staged, issue-early/
// write-late (T14). One __syncthreads per K-step.
__global__ __launch_bounds__(256) void gemm1_kernel(
    const ushort* __restrict__ xb, const float* __restrict__ w1,
    const float* __restrict__ w3, const int* __restrict__ ntiles,
    const int* __restrict__ tile_e, const int* __restrict__ tile_r0,
    const int* __restrict__ offs, const int* __restrict__ bucket,
    ushort* __restrict__ H) {
  int tile = blockIdx.y;
  if (tile >= *ntiles) return;
  int e = tile_e[tile], r0 = tile_r0[tile];
  int base = offs[e], cnt = offs[e + 1] - base;
  int f0 = blockIdx.x * 64;

  __shared__ ushort As[2][128 * 64];   // 32 KB
  __shared__ ushort B1s[2][64 * 64];   // 16 KB
  __shared__ ushort B3s[2][64 * 64];   // 16 KB

  int tid = threadIdx.x;
  int w = tid >> 6, lane = tid & 63;
  int wm = w >> 1, wn = w & 1;

  const ushort* aptr[4];
#pragma unroll
  for (int c = 0; c < 4; ++c) {
    int r = w * 32 + c * 8 + (lane >> 3);
    int rr = min(r0 + r, cnt - 1);
    int tok = bucket[base + rr];
    aptr[c] = xb + (size_t)tok * D_MODEL + (lane & 7) * 8;
  }
  int rb = tid >> 2, qb = tid & 3;
  const float4* p1 = (const float4*)(w1 + ((size_t)e * EXPERT_DIM + f0 + rb) * D_MODEL + qb * 16);
  const float4* p3 = (const float4*)(w3 + ((size_t)e * EXPERT_DIM + f0 + rb) * D_MODEL + qb * 16);
  int wslot = rb * 64 + qb * 16;

  f32x4 accU[4][2], accV[4][2];
#pragma unroll
  for (int i = 0; i < 4; ++i)
#pragma unroll
    for (int j = 0; j < 2; ++j) { accU[i][j] = (f32x4)0.f; accV[i][j] = (f32x4)0.f; }

  float4 r1[4], r3[4];
  // prologue: stage k=0
#pragma unroll
  for (int c = 0; c < 4; ++c)
    GLOAD_LDS16(aptr[c], &As[0][(w * 32 + c * 8) * 64]);
#pragma unroll
  for (int i = 0; i < 4; ++i) r1[i] = p1[i];
#pragma unroll
  for (int i = 0; i < 4; ++i) r3[i] = p3[i];
  {
    ushort* d1 = &B1s[0][wslot];
    *(short8*)d1 = pack8(r1[0], r1[1]); *(short8*)(d1 + 8) = pack8(r1[2], r1[3]);
    ushort* d3 = &B3s[0][wslot];
    *(short8*)d3 = pack8(r3[0], r3[1]); *(short8*)(d3 + 8) = pack8(r3[2], r3[3]);
  }
  __syncthreads();

  for (int k = 0; k < 16; ++k) {
    int buf = k & 1;
    if (k < 15) {
      // issue next tile's loads (A -> LDS[other], B -> regs)
#pragma unroll
      for (int c = 0; c < 4; ++c)
        GLOAD_LDS16(aptr[c] + (k + 1) * 64, &As[buf ^ 1][(w * 32 + c * 8) * 64]);
      int k4 = (k + 1) * 16;
#pragma unroll
      for (int i = 0; i < 4; ++i) r1[i] = p1[k4 + i];
#pragma unroll
      for (int i = 0; i < 4; ++i) r3[i] = p3[k4 + i];
    }
    __builtin_amdgcn_sched_barrier(0);
    // compute current tile
#pragma unroll
    for (int ks = 0; ks < 2; ++ks) {
      int ko = ks * 32 + (lane >> 4) * 8;
      short8 af[4], bf1[2], bf3[2];
#pragma unroll
      for (int i = 0; i < 4; ++i)
        af[i] = *(const short8*)&As[buf][(wm * 64 + i * 16 + (lane & 15)) * 64 + ko];
#pragma unroll
      for (int j = 0; j < 2; ++j) {
        bf1[j] = *(const short8*)&B1s[buf][(wn * 32 + j * 16 + (lane & 15)) * 64 + ko];
        bf3[j] = *(const short8*)&B3s[buf][(wn * 32 + j * 16 + (lane & 15)) * 64 + ko];
      }
#pragma unroll
      for (int i = 0; i < 4; ++i)
#pragma unroll
        for (int j = 0; j < 2; ++j) {
          accU[i][j] = __builtin_amdgcn_mfma_f32_16x16x32_bf16(af[i], bf1[j], accU[i][j], 0, 0, 0);
          accV[i][j] = __builtin_amdgcn_mfma_f32_16x16x32_bf16(af[i], bf3[j], accV[i][j], 0, 0, 0);
        }
    }
    __builtin_amdgcn_sched_barrier(0);
    if (k < 15) {
      ushort* d1 = &B1s[buf ^ 1][wslot];
      *(short8*)d1 = pack8(r1[0], r1[1]); *(short8*)(d1 + 8) = pack8(r1[2], r1[3]);
      ushort* d3 = &B3s[buf ^ 1][wslot];
      *(short8*)d3 = pack8(r3[0], r3[1]); *(short8*)(d3 + 8) = pack8(r3[2], r3[3]);
    }
    __syncthreads();
  }

  // epilogue: h = silu(u)*v -> bf16 H
#pragma unroll
  for (int i = 0; i < 4; ++i)
#pragma unroll
    for (int q = 0; q < 4; ++q) {
      int m_loc = wm * 64 + i * 16 + (lane >> 4) * 4 + q;
      if (r0 + m_loc < cnt) {
        size_t rowb = (size_t)(base + r0 + m_loc) * EXPERT_DIM + f0 + wn * 32 + (lane & 15);
#pragma unroll
        for (int j = 0; j < 2; ++j) {
          float uu = accU[i][j][q], vv = accV[i][j][q];
          float h = uu / (1.f + __expf(-uu)) * vv;
          H[rowb + j * 16] = f2b(h);
        }
      }
    }
}

// ---- GEMM2: out = (H @ w2^T) * gate; 128x64 tile; dbuf pipeline ----
__global__ __launch_bounds__(256) void gemm2_kernel(
    const ushort* __restrict__ H, const float* __restrict__ w2,
    const int* __restrict__ ntiles, const int* __restrict__ tile_e,
    const int* __restrict__ tile_r0, const int* __restrict__ offs,
    const int* __restrict__ bucket, const float* __restrict__ tok_g,
    float* __restrict__ out) {
  int tile = blockIdx.y;
  if (tile >= *ntiles) return;
  int e = tile_e[tile], r0 = tile_r0[tile];
  int base = offs[e], cnt = offs[e + 1] - base;
  int d0 = blockIdx.x * 64;

  __shared__ ushort As[2][128 * 64];   // 32 KB
  __shared__ ushort Bs[2][64 * 64];    // 16 KB

  int tid = threadIdx.x;
  int w = tid >> 6, lane = tid & 63;
  int wm = w >> 1, wn = w & 1;

  const ushort* aptr[4];
#pragma unroll
  for (int c = 0; c < 4; ++c) {
    int r = w * 32 + c * 8 + (lane >> 3);
    int rr = min(r0 + r, cnt - 1);
    aptr[c] = H + (size_t)(base + rr) * EXPERT_DIM + (lane & 7) * 8;
  }
  int rb = tid >> 2, qb = tid & 3;
  const float4* p2 = (const float4*)(w2 + ((size_t)e * D_MODEL + d0 + rb) * EXPERT_DIM + qb * 16);
  int wslot = rb * 64 + qb * 16;

  f32x4 acc[4][2];
#pragma unroll
  for (int i = 0; i < 4; ++i)
#pragma unroll
    for (int j = 0; j < 2; ++j) acc[i][j] = (f32x4)0.f;

  float4 r2[4];
#pragma unroll
  for (int c = 0; c < 4; ++c)
    GLOAD_LDS16(aptr[c], &As[0][(w * 32 + c * 8) * 64]);
#pragma unroll
  for (int i = 0; i < 4; ++i) r2[i] = p2[i];
  {
    ushort* d2 = &Bs[0][wslot];
    *(short8*)d2 = pack8(r2[0], r2[1]); *(short8*)(d2 + 8) = pack8(r2[2], r2[3]);
  }
  __syncthreads();

  for (int k = 0; k < 64; ++k) {
    int buf = k & 1;
    if (k < 63) {
#pragma unroll
      for (int c = 0; c < 4; ++c)
        GLOAD_LDS16(aptr[c] + (k + 1) * 64, &As[buf ^ 1][(w * 32 + c * 8) * 64]);
      int k4 = (k + 1) * 16;
#pragma unroll
      for (int i = 0; i < 4; ++i) r2[i] = p2[k4 + i];
    }
    __builtin_amdgcn_sched_barrier(0);
#pragma unroll
    for (int ks = 0; ks < 2; ++ks) {
      int ko = ks * 32 + (lane >> 4) * 8;
      short8 af[4], bf[2];
#pragma unroll
      for (int i = 0; i < 4; ++i)
        af[i] = *(const short8*)&As[buf][(wm * 64 + i * 16 + (lane & 15)) * 64 + ko];
#pragma unroll
      for (int j = 0; j < 2; ++j)
        bf[j] = *(const short8*)&Bs[buf][(wn * 32 + j * 16 + (lane & 15)) * 64 + ko];
#pragma unroll
      for (int i = 0; i < 4; ++i)
#pragma unroll
        for (int j = 0; j < 2; ++j)
          acc[i][j] = __builtin_amdgcn_mfma_f32_16x16x32_bf16(af[i], bf[j], acc[i][j], 0, 0, 0);
    }
    __builtin_amdgcn_sched_barrier(0);
    if (k < 63) {
      ushort* d2 = &Bs[buf ^ 1][wslot];
      *(short8*)d2 = pack8(r2[0], r2[1]); *(short8*)(d2 + 8) = pack8(r2[2], r2[3]);
    }
    __syncthreads();
  }

#pragma unroll
  for (int i = 0; i < 4; ++i)
#pragma unroll
    for (int q = 0; q < 4; ++q) {
      int m_loc = wm * 64 + i * 16 + (lane >> 4) * 4 + q;
      if (r0 + m_loc < cnt) {
        int tok = bucket[base + r0 + m_loc];
        float g = tok_g[tok];
        float* op = out + (size_t)tok * D_MODEL + d0 + wn * 32 + (lane & 15);
#pragma unroll
        for (int j = 0; j < 2; ++j)
          op[j * 16] = acc[i][j][q] * g;
      }
    }
}

extern "C" void kernel_launch(void* const* d_in, const int* in_sizes, int n_in,
                              void* d_out, int out_size, void* d_ws, size_t ws_size,
                              hipStream_t stream) {
  const float* x  = (const float*)d_in[0];
  const float* gw = (const float*)d_in[1];
  const float* w1 = (const float*)d_in[2];
  const float* w2 = (const float*)d_in[3];
  const float* w3 = (const float*)d_in[4];
  float* out = (float*)d_out;
  char* ws = (char*)d_ws;

  float* probs = (float*)(ws + OFF_PROBS);
  int* tok_e   = (int*)(ws + OFF_EXP);
  float* tok_g = (float*)(ws + OFF_GATE);
  int* cnt     = (int*)(ws + OFF_CNT);
  int* cur     = (int*)(ws + OFF_CUR);
  float* simp  = (float*)(ws + OFF_SIMP);
  int* offs    = (int*)(ws + OFF_OFFS);
  int* ntiles  = (int*)(ws + OFF_NT);
  int* tile_e  = (int*)(ws + OFF_TE);
  int* tile_r0 = (int*)(ws + OFF_TR);
  int* bucket  = (int*)(ws + OFF_BUCKET);
  ushort* xb   = (ushort*)(ws + OFF_XB);
  ushort* H    = (ushort*)(ws + OFF_H);

  hipMemsetAsync(ws + OFF_CNT, 0, 96, stream);  // cnt + cursor + simp
  gate_kernel<<<N_TOKENS / 4, 256, 0, stream>>>(x, gw, probs, tok_e, tok_g, cnt, xb);
  imp_kernel<<<N_TOKENS / 256, 256, 0, stream>>>(probs, simp);
  plan_kernel<<<1, 64, 0, stream>>>(cnt, simp, offs, ntiles, tile_e, tile_r0,
                                    out + (size_t)N_TOKENS * D_MODEL);
  scatter_kernel<<<N_TOKENS / 256, 256, 0, stream>>>(tok_e, cur, offs, bucket);
  gemm1_kernel<<<dim3(EXPERT_DIM / 64, MAX_TILES), 256, 0, stream>>>(
      xb, w1, w3, ntiles, tile_e, tile_r0, offs, bucket, H);
  gemm2_kernel<<<dim3(D_MODEL / 64, MAX_TILES), 256, 0, stream>>>(
      H, w2, ntiles, tile_e, tile_r0, offs, bucket, tok_g, out);
}